// Round 17
// baseline (273.604 us; speedup 1.0000x reference)
//
#include <hip/hip_runtime.h>
#include <stdint.h>

#define NROWS 16384
#define D 4096

typedef __bf16 bf16x8 __attribute__((ext_vector_type(8)));
typedef float  f32x4  __attribute__((ext_vector_type(4)));

__device__ inline unsigned short f2bf(float f) {
    unsigned u = __float_as_uint(f);
    u += 0x7fffu + ((u >> 16) & 1u);
    return (unsigned short)(u >> 16);
}

// ---------------- core -> bf16 in GEMM staging layout ----------------
__global__ __launch_bounds__(256) void k_corebf(const float* __restrict__ core,
                                                unsigned int* __restrict__ cb) {
    const int o = blockIdx.x;            // 512
    const int kp = threadIdx.x;          // bf16-pair index, k = 2*kp
    float2 v = *(const float2*)&core[o * 512 + 2 * kp];
    cb[((size_t)(kp >> 2) * 512 + o) * 4 + (kp & 3)] =
        (unsigned)f2bf(v.x) | ((unsigned)f2bf(v.y) << 16);
}

// ---------------- input contraction: 4 rows/block, dbuf pipeline ----------------
// (byte-identical to round 12 — verified)
__global__ __launch_bounds__(256, 3) void k_t3(const float* __restrict__ x,
                                               const float* __restrict__ fi0,
                                               const float* __restrict__ fi1,
                                               const float* __restrict__ fi2,
                                               const int* __restrict__ perm,
                                               unsigned int* __restrict__ t3out) {
    __shared__ float xr[2][4096];  // 32 KB, double-buffered un-permuted rows
    __shared__ float t1[2048];     //  8 KB
    __shared__ float t2[1024];     //  4 KB
    __shared__ float fac[3][128];  //  1.5 KB

    const int tid = threadIdx.x;
    const int n0 = blockIdx.x * 4;

    {
        const int h = tid & 127;
        fac[0][h] = fi0[h];
        fac[1][h] = fi1[h];
        fac[2][h] = fi2[h];
    }
    int pj[16];
    #pragma unroll
    for (int j = 0; j < 16; ++j) pj[j] = perm[j * 256 + tid];

    auto stage = [&](int b, int row) {
        const float4* src = (const float4*)(x + (size_t)row * D);
        #pragma unroll
        for (int i = 0; i < 4; ++i) {
            const int c = i * 256 + tid;
            __builtin_amdgcn_global_load_lds(
                (const __attribute__((address_space(1))) void*)(src + c),
                (__attribute__((address_space(3))) void*)(&xr[b][c * 4]),
                16, 0, 0);
        }
    };

    auto STEP3 = [&](int b) {
        float a8[8] = {0,0,0,0,0,0,0,0};
        #pragma unroll
        for (int a = 0; a < 16; ++a) {
            float v = xr[b][pj[a]];
            #pragma unroll
            for (int p = 0; p < 8; ++p) a8[p] += v * fac[0][a * 8 + p];
        }
        #pragma unroll
        for (int p = 0; p < 8; ++p) t1[p * 256 + tid] = a8[p];
    };
    auto STEP4 = [&]() {
        const int p = tid >> 5, c = (tid >> 1) & 15, qh = tid & 1;
        float a4[4] = {0,0,0,0};
        #pragma unroll
        for (int b = 0; b < 16; ++b) {
            float v = t1[p * 256 + b * 16 + c];
            #pragma unroll
            for (int qi = 0; qi < 4; ++qi) a4[qi] += v * fac[1][b * 8 + qh * 4 + qi];
        }
        #pragma unroll
        for (int qi = 0; qi < 4; ++qi) t2[p * 128 + (qh * 4 + qi) * 16 + c] = a4[qi];
    };
    auto STEP5_PACK = [&](int n) {
        const int p = tid >> 5, q = (tid >> 2) & 7, rh = tid & 3;
        float a2[2] = {0,0};
        #pragma unroll
        for (int c = 0; c < 16; ++c) {
            float v = t2[p * 128 + q * 16 + c];
            #pragma unroll
            for (int ri = 0; ri < 2; ++ri) a2[ri] += v * fac[2][c * 8 + rh * 2 + ri];
        }
        const int kt = tid >> 5, k4 = (tid >> 2) & 7, w = tid & 3;
        t3out[(((size_t)kt * 8 + k4) * NROWS + n) * 4 + w] =
            (unsigned)f2bf(a2[0]) | ((unsigned)f2bf(a2[1]) << 16);
    };

    stage(0, n0 + 0);
    stage(1, n0 + 1);

    asm volatile("s_waitcnt vmcnt(4) lgkmcnt(0)" ::: "memory");
    __builtin_amdgcn_s_barrier();
    STEP3(0);
    asm volatile("s_waitcnt lgkmcnt(0)" ::: "memory");
    __builtin_amdgcn_s_barrier();
    stage(0, n0 + 2);
    STEP4();
    asm volatile("s_waitcnt lgkmcnt(0)" ::: "memory");
    __builtin_amdgcn_s_barrier();
    STEP5_PACK(n0 + 0);

    asm volatile("s_waitcnt vmcnt(5)" ::: "memory");
    __builtin_amdgcn_s_barrier();
    STEP3(1);
    asm volatile("s_waitcnt lgkmcnt(0)" ::: "memory");
    __builtin_amdgcn_s_barrier();
    stage(1, n0 + 3);
    STEP4();
    asm volatile("s_waitcnt lgkmcnt(0)" ::: "memory");
    __builtin_amdgcn_s_barrier();
    STEP5_PACK(n0 + 1);

    asm volatile("s_waitcnt vmcnt(6)" ::: "memory");
    __builtin_amdgcn_s_barrier();
    STEP3(0);
    asm volatile("s_waitcnt lgkmcnt(0)" ::: "memory");
    __builtin_amdgcn_s_barrier();
    STEP4();
    asm volatile("s_waitcnt lgkmcnt(0)" ::: "memory");
    __builtin_amdgcn_s_barrier();
    STEP5_PACK(n0 + 2);

    asm volatile("s_waitcnt vmcnt(2)" ::: "memory");
    __builtin_amdgcn_s_barrier();
    STEP3(1);
    asm volatile("s_waitcnt lgkmcnt(0)" ::: "memory");
    __builtin_amdgcn_s_barrier();
    STEP4();
    asm volatile("s_waitcnt lgkmcnt(0)" ::: "memory");
    __builtin_amdgcn_s_barrier();
    STEP5_PACK(n0 + 3);
}

// ---------------- core GEMM: t4[n][512] = t3[n][512] @ core^T (bf16 out) ------
// (byte-identical to round 12 — verified; launched TWICE for attribution)
__global__ __launch_bounds__(256, 2) void k_core(const __bf16* __restrict__ t3,
                                                 const __bf16* __restrict__ cb,
                                                 unsigned short* __restrict__ t4) {
    __shared__ __bf16 lA[2][8192];   // [buf][k4][row][8]  2x16 KB
    __shared__ __bf16 lB[2][8192];   //                    2x16 KB

    const int tid = threadIdx.x, lane = tid & 63, wv = tid >> 6;

    const int bid = blockIdx.x;
    const int wgid = (bid & 7) * 64 + (bid >> 3);
    const int m0 = (wgid >> 2) * 128;
    const int n0 = (wgid & 3) * 128;
    const int wm = wv >> 1, wn = wv & 1;
    const int l15 = lane & 15, l4 = lane >> 4;

    auto stage = [&](int b, int kt) {
        #pragma unroll
        for (int i = 0; i < 4; ++i) {
            const int c = i * 256 + tid;
            const int k4 = c >> 7, r = c & 127;
            const __bf16* ga = t3 + ((size_t)(kt * 8 + k4) * NROWS + m0 + r) * 8;
            __builtin_amdgcn_global_load_lds(
                (const __attribute__((address_space(1))) void*)ga,
                (__attribute__((address_space(3))) void*)(&lA[b][(size_t)c * 8]),
                16, 0, 0);
            const __bf16* gb = cb + ((size_t)(kt * 8 + k4) * 512 + n0 + r) * 8;
            __builtin_amdgcn_global_load_lds(
                (const __attribute__((address_space(1))) void*)gb,
                (__attribute__((address_space(3))) void*)(&lB[b][(size_t)c * 8]),
                16, 0, 0);
        }
    };

    f32x4 acc[4][4] = {};

    auto compute = [&](int cur) {
        #pragma unroll
        for (int kk = 0; kk < 2; ++kk) {
            const int k4f = kk * 4 + l4;
            bf16x8 af[4], bfr[4];
            #pragma unroll
            for (int mt = 0; mt < 4; ++mt)
                af[mt] = *(const bf16x8*)&lA[cur][(k4f * 128 + wm * 64 + mt * 16 + l15) * 8];
            #pragma unroll
            for (int nt = 0; nt < 4; ++nt)
                bfr[nt] = *(const bf16x8*)&lB[cur][(k4f * 128 + wn * 64 + nt * 16 + l15) * 8];
            #pragma unroll
            for (int mt = 0; mt < 4; ++mt)
                #pragma unroll
                for (int nt = 0; nt < 4; ++nt)
                    acc[mt][nt] = __builtin_amdgcn_mfma_f32_16x16x32_bf16(
                        af[mt], bfr[nt], acc[mt][nt], 0, 0, 0);
        }
    };

    stage(0, 0);
    stage(1, 1);
    #pragma unroll 1
    for (int kt = 0; kt < 8; ++kt) {
        if (kt < 7) asm volatile("s_waitcnt vmcnt(8)" ::: "memory");
        else        asm volatile("s_waitcnt vmcnt(0)" ::: "memory");
        __builtin_amdgcn_s_barrier();
        __builtin_amdgcn_s_setprio(1);
        compute(kt & 1);
        __builtin_amdgcn_s_setprio(0);
        __builtin_amdgcn_s_barrier();
        if (kt < 6) stage(kt & 1, kt + 2);
    }

    #pragma unroll
    for (int nt = 0; nt < 4; ++nt) {
        const int col = n0 + wn * 64 + nt * 16 + l15;
        #pragma unroll
        for (int mt = 0; mt < 4; ++mt) {
            const int row = m0 + wm * 64 + mt * 16 + l4 * 4;
            #pragma unroll
            for (int j = 0; j < 4; ++j)
                t4[(size_t)(row + j) * 512 + col] = f2bf(acc[mt][nt][j]);
        }
    }
}

// ---------------- output expansion v3: wave-per-row, coalesced stores ----------
// (byte-identical to round 16 — verified; launched TWICE for attribution)
__global__ __launch_bounds__(256, 2) void k_expand(const unsigned short* __restrict__ t4,
                                                   const float* __restrict__ fo0,
                                                   const float* __restrict__ fo1,
                                                   const float* __restrict__ fo2,
                                                   const float* __restrict__ pds,
                                                   const float* __restrict__ alphap,
                                                   const float* __restrict__ bias,
                                                   float* __restrict__ out) {
    __shared__ __bf16 t4L[4][2][512];   //  8 KB  per-wave dbuf t4 rows
    __shared__ float  t5L[4][1024];     // 16 KB  [w][X*64 + z*8 + y]
    __shared__ float  t6L[4][2304];     // 36 KB  [w][(X*16+Y)*9 + z]
    __shared__ float  fo0L[128];        // 0.5 KB

    const int tid = threadIdx.x, w = tid >> 6, l = tid & 63;
    const int n0 = blockIdx.x * 32 + w * 8;
    const int ly = l >> 3, lz = l & 7;     // (y, z) role in phase A/B
    const int lq = l & 3, lx = l >> 2;     // (Z-quad, XY-sub) role in phase C

    if (tid < 128) fo0L[tid] = fo0[tid];
    const float alpha = alphap[0];

    float fo1f[2][8];                      // fo1[(ly + 8h)*8 + y]
    #pragma unroll
    for (int h = 0; h < 2; ++h) {
        f32x4 a = *(const f32x4*)&fo1[(h * 8 + ly) * 8];
        f32x4 b = *(const f32x4*)&fo1[(h * 8 + ly) * 8 + 4];
        #pragma unroll
        for (int j = 0; j < 4; ++j) { fo1f[h][j] = a[j]; fo1f[h][4 + j] = b[j]; }
    }
    float fo2s[4][8];                      // fo2[(lq*4+j)*8 + z] slice
    #pragma unroll
    for (int j = 0; j < 4; ++j) {
        f32x4 a = *(const f32x4*)&fo2[(lq * 4 + j) * 8];
        f32x4 b = *(const f32x4*)&fo2[(lq * 4 + j) * 8 + 4];
        #pragma unroll
        for (int zz = 0; zz < 4; ++zz) { fo2s[j][zz] = a[zz]; fo2s[j][4 + zz] = b[zz]; }
    }

    auto stage = [&](int b, int n) {
        const unsigned short* src = t4 + (size_t)n * 512 + l * 8;
        __builtin_amdgcn_global_load_lds(
            (const __attribute__((address_space(1))) void*)src,
            (__attribute__((address_space(3))) void*)(&t4L[w][b][l * 8]),
            16, 0, 0);
    };

    stage(0, n0);
    asm volatile("s_waitcnt vmcnt(0) lgkmcnt(0)" ::: "memory");
    __syncthreads();                       // fo0L + first t4 row visible

    #pragma unroll 1
    for (int r = 0; r < 8; ++r) {
        const int b = r & 1;
        if (r) asm volatile("s_waitcnt vmcnt(48)" ::: "memory");  // stage(r) done

        // ---- phase A: rv[x] = t4[x*64+l]; t5[X][lz][ly] ----
        float rv[8];
        #pragma unroll
        for (int xx = 0; xx < 8; ++xx)
            rv[xx] = (float)t4L[w][b][xx * 64 + l];
        if (r + 1 < 8) stage(b ^ 1, n0 + r + 1);   // prefetch next row
        #pragma unroll
        for (int X = 0; X < 16; ++X) {
            f32x4 f0 = *(const f32x4*)&fo0L[X * 8];
            f32x4 f1 = *(const f32x4*)&fo0L[X * 8 + 4];
            float s = rv[0] * f0[0] + rv[1] * f0[1] + rv[2] * f0[2] + rv[3] * f0[3]
                    + rv[4] * f1[0] + rv[5] * f1[1] + rv[6] * f1[2] + rv[7] * f1[3];
            t5L[w][X * 64 + lz * 8 + ly] = s;
        }
        asm volatile("s_waitcnt lgkmcnt(0)" ::: "memory");

        // ---- phase B: lane (Y2=ly, z=lz); t6[X][Y][lz] for Y=ly, ly+8 ----
        #pragma unroll
        for (int X = 0; X < 16; ++X) {
            f32x4 u0 = *(const f32x4*)&t5L[w][X * 64 + lz * 8];
            f32x4 u1 = *(const f32x4*)&t5L[w][X * 64 + lz * 8 + 4];
            float a0 = u0[0] * fo1f[0][0] + u0[1] * fo1f[0][1] + u0[2] * fo1f[0][2] + u0[3] * fo1f[0][3]
                     + u1[0] * fo1f[0][4] + u1[1] * fo1f[0][5] + u1[2] * fo1f[0][6] + u1[3] * fo1f[0][7];
            float a1 = u0[0] * fo1f[1][0] + u0[1] * fo1f[1][1] + u0[2] * fo1f[1][2] + u0[3] * fo1f[1][3]
                     + u1[0] * fo1f[1][4] + u1[1] * fo1f[1][5] + u1[2] * fo1f[1][6] + u1[3] * fo1f[1][7];
            t6L[w][(X * 16 + ly) * 9 + lz]     = a0;
            t6L[w][(X * 16 + ly + 8) * 9 + lz] = a1;
        }
        asm volatile("s_waitcnt lgkmcnt(0)" ::: "memory");

        // ---- phase C: lane-contiguous loads/stores ----
        float* orow = out + (size_t)(n0 + r) * 4096;
        #pragma unroll
        for (int c2 = 0; c2 < 16; ++c2) {
            const int XY = c2 * 16 + lx;
            f32x4 pq = *(const f32x4*)&pds[c2 * 256 + l * 4];
            f32x4 bq = *(const f32x4*)&bias[c2 * 256 + l * 4];
            float tv[8];
            #pragma unroll
            for (int zz = 0; zz < 8; ++zz) tv[zz] = t6L[w][XY * 9 + zz];
            f32x4 o4;
            #pragma unroll
            for (int j = 0; j < 4; ++j) {
                float t7 = tv[0] * fo2s[j][0] + tv[1] * fo2s[j][1]
                         + tv[2] * fo2s[j][2] + tv[3] * fo2s[j][3]
                         + tv[4] * fo2s[j][4] + tv[5] * fo2s[j][5]
                         + tv[6] * fo2s[j][6] + tv[7] * fo2s[j][7];
                o4[j] = t7 * (pq[j] * alpha) + bq[j];
            }
            *(f32x4*)&orow[c2 * 256 + l * 4] = o4;
        }
    }
}

extern "C" void kernel_launch(void* const* d_in, const int* in_sizes, int n_in,
                              void* d_out, int out_size, void* d_ws, size_t ws_size,
                              hipStream_t stream) {
    const float* x     = (const float*)d_in[0];
    const float* core  = (const float*)d_in[1];
    const float* fi0   = (const float*)d_in[2];
    const float* fi1   = (const float*)d_in[3];
    const float* fi2   = (const float*)d_in[4];
    const float* fo0   = (const float*)d_in[5];
    const float* fo1   = (const float*)d_in[6];
    const float* fo2   = (const float*)d_in[7];
    const float* pds   = (const float*)d_in[8];
    const float* alpha = (const float*)d_in[9];
    const float* bias  = (const float*)d_in[10];
    const int*   perm  = (const int*)d_in[11];
    float* outp = (float*)d_out;

    char* ws = (char*)d_ws;
    unsigned int*   cb   = (unsigned int*)(ws);                   // 512 KB
    unsigned int*   t3ws = (unsigned int*)(ws + 1048576);         // 16 MB
    unsigned short* t4   = (unsigned short*)(ws + 17825792);      // 16.75 MB

    k_corebf<<<512, 256, 0, stream>>>(core, cb);
    k_t3<<<NROWS / 4, 256, 0, stream>>>(x, fi0, fi1, fi2, perm, t3ws);
    // ATTRIBUTION ROUND: k_core and k_expand each launched twice (idempotent,
    // deterministic). T - 174.0 == core_dur + expand_dur.
    k_core<<<512, 256, 0, stream>>>((const __bf16*)t3ws, (const __bf16*)cb, t4);
    k_core<<<512, 256, 0, stream>>>((const __bf16*)t3ws, (const __bf16*)cb, t4);
    k_expand<<<512, 256, 0, stream>>>(t4, fo0, fo1, fo2, pds, alpha, bias, outp);
    k_expand<<<512, 256, 0, stream>>>(t4, fo0, fo1, fo2, pds, alpha, bias, outp);
}

// Round 18
// 269.393 us; speedup vs baseline: 1.0156x; 1.0156x over previous
//
#include <hip/hip_runtime.h>
#include <stdint.h>

#define NROWS 16384
#define D 4096

typedef __bf16 bf16x8 __attribute__((ext_vector_type(8)));
typedef float  f32x4  __attribute__((ext_vector_type(4)));

__device__ inline unsigned short f2bf(float f) {
    unsigned u = __float_as_uint(f);
    u += 0x7fffu + ((u >> 16) & 1u);
    return (unsigned short)(u >> 16);
}

// ---------------- core -> bf16 in GEMM staging layout ----------------
__global__ __launch_bounds__(256) void k_corebf(const float* __restrict__ core,
                                                unsigned int* __restrict__ cb) {
    const int o = blockIdx.x;            // 512
    const int kp = threadIdx.x;          // bf16-pair index, k = 2*kp
    float2 v = *(const float2*)&core[o * 512 + 2 * kp];
    cb[((size_t)(kp >> 2) * 512 + o) * 4 + (kp & 3)] =
        (unsigned)f2bf(v.x) | ((unsigned)f2bf(v.y) << 16);
}

// ---------------- input contraction: 4 rows/block, dbuf pipeline ----------------
// (byte-identical to round 12 — verified)
__global__ __launch_bounds__(256, 3) void k_t3(const float* __restrict__ x,
                                               const float* __restrict__ fi0,
                                               const float* __restrict__ fi1,
                                               const float* __restrict__ fi2,
                                               const int* __restrict__ perm,
                                               unsigned int* __restrict__ t3out) {
    __shared__ float xr[2][4096];  // 32 KB, double-buffered un-permuted rows
    __shared__ float t1[2048];     //  8 KB
    __shared__ float t2[1024];     //  4 KB
    __shared__ float fac[3][128];  //  1.5 KB

    const int tid = threadIdx.x;
    const int n0 = blockIdx.x * 4;

    {
        const int h = tid & 127;
        fac[0][h] = fi0[h];
        fac[1][h] = fi1[h];
        fac[2][h] = fi2[h];
    }
    int pj[16];
    #pragma unroll
    for (int j = 0; j < 16; ++j) pj[j] = perm[j * 256 + tid];

    auto stage = [&](int b, int row) {
        const float4* src = (const float4*)(x + (size_t)row * D);
        #pragma unroll
        for (int i = 0; i < 4; ++i) {
            const int c = i * 256 + tid;
            __builtin_amdgcn_global_load_lds(
                (const __attribute__((address_space(1))) void*)(src + c),
                (__attribute__((address_space(3))) void*)(&xr[b][c * 4]),
                16, 0, 0);
        }
    };

    auto STEP3 = [&](int b) {
        float a8[8] = {0,0,0,0,0,0,0,0};
        #pragma unroll
        for (int a = 0; a < 16; ++a) {
            float v = xr[b][pj[a]];
            #pragma unroll
            for (int p = 0; p < 8; ++p) a8[p] += v * fac[0][a * 8 + p];
        }
        #pragma unroll
        for (int p = 0; p < 8; ++p) t1[p * 256 + tid] = a8[p];
    };
    auto STEP4 = [&]() {
        const int p = tid >> 5, c = (tid >> 1) & 15, qh = tid & 1;
        float a4[4] = {0,0,0,0};
        #pragma unroll
        for (int b = 0; b < 16; ++b) {
            float v = t1[p * 256 + b * 16 + c];
            #pragma unroll
            for (int qi = 0; qi < 4; ++qi) a4[qi] += v * fac[1][b * 8 + qh * 4 + qi];
        }
        #pragma unroll
        for (int qi = 0; qi < 4; ++qi) t2[p * 128 + (qh * 4 + qi) * 16 + c] = a4[qi];
    };
    auto STEP5_PACK = [&](int n) {
        const int p = tid >> 5, q = (tid >> 2) & 7, rh = tid & 3;
        float a2[2] = {0,0};
        #pragma unroll
        for (int c = 0; c < 16; ++c) {
            float v = t2[p * 128 + q * 16 + c];
            #pragma unroll
            for (int ri = 0; ri < 2; ++ri) a2[ri] += v * fac[2][c * 8 + rh * 2 + ri];
        }
        const int kt = tid >> 5, k4 = (tid >> 2) & 7, w = tid & 3;
        t3out[(((size_t)kt * 8 + k4) * NROWS + n) * 4 + w] =
            (unsigned)f2bf(a2[0]) | ((unsigned)f2bf(a2[1]) << 16);
    };

    stage(0, n0 + 0);
    stage(1, n0 + 1);

    asm volatile("s_waitcnt vmcnt(4) lgkmcnt(0)" ::: "memory");
    __builtin_amdgcn_s_barrier();
    STEP3(0);
    asm volatile("s_waitcnt lgkmcnt(0)" ::: "memory");
    __builtin_amdgcn_s_barrier();
    stage(0, n0 + 2);
    STEP4();
    asm volatile("s_waitcnt lgkmcnt(0)" ::: "memory");
    __builtin_amdgcn_s_barrier();
    STEP5_PACK(n0 + 0);

    asm volatile("s_waitcnt vmcnt(5)" ::: "memory");
    __builtin_amdgcn_s_barrier();
    STEP3(1);
    asm volatile("s_waitcnt lgkmcnt(0)" ::: "memory");
    __builtin_amdgcn_s_barrier();
    stage(1, n0 + 3);
    STEP4();
    asm volatile("s_waitcnt lgkmcnt(0)" ::: "memory");
    __builtin_amdgcn_s_barrier();
    STEP5_PACK(n0 + 1);

    asm volatile("s_waitcnt vmcnt(6)" ::: "memory");
    __builtin_amdgcn_s_barrier();
    STEP3(0);
    asm volatile("s_waitcnt lgkmcnt(0)" ::: "memory");
    __builtin_amdgcn_s_barrier();
    STEP4();
    asm volatile("s_waitcnt lgkmcnt(0)" ::: "memory");
    __builtin_amdgcn_s_barrier();
    STEP5_PACK(n0 + 2);

    asm volatile("s_waitcnt vmcnt(2)" ::: "memory");
    __builtin_amdgcn_s_barrier();
    STEP3(1);
    asm volatile("s_waitcnt lgkmcnt(0)" ::: "memory");
    __builtin_amdgcn_s_barrier();
    STEP4();
    asm volatile("s_waitcnt lgkmcnt(0)" ::: "memory");
    __builtin_amdgcn_s_barrier();
    STEP5_PACK(n0 + 3);
}

// ---------------- core GEMM: t4[n][512] = t3[n][512] @ core^T (bf16 out) ------
// Round-12 structure; epilogue now stores t4 TRANSPOSED per row:
//   t4[n*512 + (o&63)*8 + (o>>6)]  (o = output index = x*64 + yz)
// so k_expand can read lane-contiguous 16 B per row (o = col below).
__global__ __launch_bounds__(256, 2) void k_core(const __bf16* __restrict__ t3,
                                                 const __bf16* __restrict__ cb,
                                                 unsigned short* __restrict__ t4) {
    __shared__ __bf16 lA[2][8192];   // [buf][k4][row][8]  2x16 KB
    __shared__ __bf16 lB[2][8192];   //                    2x16 KB

    const int tid = threadIdx.x, lane = tid & 63, wv = tid >> 6;

    const int bid = blockIdx.x;
    const int wgid = (bid & 7) * 64 + (bid >> 3);
    const int m0 = (wgid >> 2) * 128;
    const int n0 = (wgid & 3) * 128;
    const int wm = wv >> 1, wn = wv & 1;
    const int l15 = lane & 15, l4 = lane >> 4;

    auto stage = [&](int b, int kt) {
        #pragma unroll
        for (int i = 0; i < 4; ++i) {
            const int c = i * 256 + tid;
            const int k4 = c >> 7, r = c & 127;
            const __bf16* ga = t3 + ((size_t)(kt * 8 + k4) * NROWS + m0 + r) * 8;
            __builtin_amdgcn_global_load_lds(
                (const __attribute__((address_space(1))) void*)ga,
                (__attribute__((address_space(3))) void*)(&lA[b][(size_t)c * 8]),
                16, 0, 0);
            const __bf16* gb = cb + ((size_t)(kt * 8 + k4) * 512 + n0 + r) * 8;
            __builtin_amdgcn_global_load_lds(
                (const __attribute__((address_space(1))) void*)gb,
                (__attribute__((address_space(3))) void*)(&lB[b][(size_t)c * 8]),
                16, 0, 0);
        }
    };

    f32x4 acc[4][4] = {};

    auto compute = [&](int cur) {
        #pragma unroll
        for (int kk = 0; kk < 2; ++kk) {
            const int k4f = kk * 4 + l4;
            bf16x8 af[4], bfr[4];
            #pragma unroll
            for (int mt = 0; mt < 4; ++mt)
                af[mt] = *(const bf16x8*)&lA[cur][(k4f * 128 + wm * 64 + mt * 16 + l15) * 8];
            #pragma unroll
            for (int nt = 0; nt < 4; ++nt)
                bfr[nt] = *(const bf16x8*)&lB[cur][(k4f * 128 + wn * 64 + nt * 16 + l15) * 8];
            #pragma unroll
            for (int mt = 0; mt < 4; ++mt)
                #pragma unroll
                for (int nt = 0; nt < 4; ++nt)
                    acc[mt][nt] = __builtin_amdgcn_mfma_f32_16x16x32_bf16(
                        af[mt], bfr[nt], acc[mt][nt], 0, 0, 0);
        }
    };

    stage(0, 0);
    stage(1, 1);
    #pragma unroll 1
    for (int kt = 0; kt < 8; ++kt) {
        if (kt < 7) asm volatile("s_waitcnt vmcnt(8)" ::: "memory");
        else        asm volatile("s_waitcnt vmcnt(0)" ::: "memory");
        __builtin_amdgcn_s_barrier();
        __builtin_amdgcn_s_setprio(1);
        compute(kt & 1);
        __builtin_amdgcn_s_setprio(0);
        __builtin_amdgcn_s_barrier();
        if (kt < 6) stage(kt & 1, kt + 2);
    }

    // epilogue: pack bf16 into TRANSPOSED per-row layout
    #pragma unroll
    for (int nt = 0; nt < 4; ++nt) {
        const int col = n0 + wn * 64 + nt * 16 + l15;     // o index
        const int oo = (col & 63) * 8 + (col >> 6);       // transposed offset
        #pragma unroll
        for (int mt = 0; mt < 4; ++mt) {
            const int row = m0 + wm * 64 + mt * 16 + l4 * 4;
            #pragma unroll
            for (int j = 0; j < 4; ++j)
                t4[(size_t)(row + j) * 512 + oo] = f2bf(acc[mt][nt][j]);
        }
    }
}

// ---------------- output expansion v4: reg-staged t4, 3 blocks/CU ----------------
// v3 + (1) t4 transposed layout -> lane l loads its 8 x-values as ONE coalesced
// 16 B global load straight to registers (no LDS staging, no scalar ds_read_u16);
// (2) LDS 52.5 KB -> 3 blocks/CU (12 waves). Named va/vb register dbuf (rule #20),
// 2-row unrolled loop. Phases B/C identical to v3 (t6 stride-9 conflict-free,
// lane-contiguous stores).
__global__ __launch_bounds__(256, 3) void k_expand(const unsigned short* __restrict__ t4,
                                                   const float* __restrict__ fo0,
                                                   const float* __restrict__ fo1,
                                                   const float* __restrict__ fo2,
                                                   const float* __restrict__ pds,
                                                   const float* __restrict__ alphap,
                                                   const float* __restrict__ bias,
                                                   float* __restrict__ out) {
    __shared__ float  t5L[4][1024];     // 16 KB  [w][X*64 + z*8 + y]
    __shared__ float  t6L[4][2304];     // 36 KB  [w][(X*16+Y)*9 + z]
    __shared__ float  fo0L[128];        // 0.5 KB

    const int tid = threadIdx.x, w = tid >> 6, l = tid & 63;
    const int n0 = blockIdx.x * 32 + w * 8;
    const int ly = l >> 3, lz = l & 7;     // (y, z) role in phase A/B
    const int lq = l & 3, lx = l >> 2;     // (Z-quad, XY-sub) role in phase C

    if (tid < 128) fo0L[tid] = fo0[tid];
    const float alpha = alphap[0];

    float fo1f[2][8];                      // fo1[(ly + 8h)*8 + y]
    #pragma unroll
    for (int h = 0; h < 2; ++h) {
        f32x4 a = *(const f32x4*)&fo1[(h * 8 + ly) * 8];
        f32x4 b = *(const f32x4*)&fo1[(h * 8 + ly) * 8 + 4];
        #pragma unroll
        for (int j = 0; j < 4; ++j) { fo1f[h][j] = a[j]; fo1f[h][4 + j] = b[j]; }
    }
    float fo2s[4][8];                      // fo2[(lq*4+j)*8 + z] slice
    #pragma unroll
    for (int j = 0; j < 4; ++j) {
        f32x4 a = *(const f32x4*)&fo2[(lq * 4 + j) * 8];
        f32x4 b = *(const f32x4*)&fo2[(lq * 4 + j) * 8 + 4];
        #pragma unroll
        for (int zz = 0; zz < 4; ++zz) { fo2s[j][zz] = a[zz]; fo2s[j][4 + zz] = b[zz]; }
    }

    // lane l owns yz = l: 8 contiguous bf16 at t4[n*512 + l*8] (transposed layout)
    auto loadrow = [&](int n) -> bf16x8 {
        return *(const bf16x8*)(t4 + (size_t)n * 512 + l * 8);
    };

    auto ROW = [&](bf16x8 vcur, int r) {
        // ---- phase A: rv[x] from registers; t5[X][lz][ly] ----
        float rv[8];
        #pragma unroll
        for (int xx = 0; xx < 8; ++xx) rv[xx] = (float)vcur[xx];
        #pragma unroll
        for (int X = 0; X < 16; ++X) {
            f32x4 f0 = *(const f32x4*)&fo0L[X * 8];
            f32x4 f1 = *(const f32x4*)&fo0L[X * 8 + 4];
            float s = rv[0] * f0[0] + rv[1] * f0[1] + rv[2] * f0[2] + rv[3] * f0[3]
                    + rv[4] * f1[0] + rv[5] * f1[1] + rv[6] * f1[2] + rv[7] * f1[3];
            t5L[w][X * 64 + lz * 8 + ly] = s;
        }
        asm volatile("s_waitcnt lgkmcnt(0)" ::: "memory");

        // ---- phase B: lane (Y2=ly, z=lz); t6[X][Y][lz] for Y=ly, ly+8 ----
        #pragma unroll
        for (int X = 0; X < 16; ++X) {
            f32x4 u0 = *(const f32x4*)&t5L[w][X * 64 + lz * 8];
            f32x4 u1 = *(const f32x4*)&t5L[w][X * 64 + lz * 8 + 4];
            float a0 = u0[0] * fo1f[0][0] + u0[1] * fo1f[0][1] + u0[2] * fo1f[0][2] + u0[3] * fo1f[0][3]
                     + u1[0] * fo1f[0][4] + u1[1] * fo1f[0][5] + u1[2] * fo1f[0][6] + u1[3] * fo1f[0][7];
            float a1 = u0[0] * fo1f[1][0] + u0[1] * fo1f[1][1] + u0[2] * fo1f[1][2] + u0[3] * fo1f[1][3]
                     + u1[0] * fo1f[1][4] + u1[1] * fo1f[1][5] + u1[2] * fo1f[1][6] + u1[3] * fo1f[1][7];
            t6L[w][(X * 16 + ly) * 9 + lz]     = a0;
            t6L[w][(X * 16 + ly + 8) * 9 + lz] = a1;
        }
        asm volatile("s_waitcnt lgkmcnt(0)" ::: "memory");

        // ---- phase C: lane-contiguous loads/stores ----
        float* orow = out + (size_t)(n0 + r) * 4096;
        #pragma unroll
        for (int c2 = 0; c2 < 16; ++c2) {
            const int XY = c2 * 16 + lx;
            f32x4 pq = *(const f32x4*)&pds[c2 * 256 + l * 4];
            f32x4 bq = *(const f32x4*)&bias[c2 * 256 + l * 4];
            float tv[8];
            #pragma unroll
            for (int zz = 0; zz < 8; ++zz) tv[zz] = t6L[w][XY * 9 + zz];
            f32x4 o4;
            #pragma unroll
            for (int j = 0; j < 4; ++j) {
                float t7 = tv[0] * fo2s[j][0] + tv[1] * fo2s[j][1]
                         + tv[2] * fo2s[j][2] + tv[3] * fo2s[j][3]
                         + tv[4] * fo2s[j][4] + tv[5] * fo2s[j][5]
                         + tv[6] * fo2s[j][6] + tv[7] * fo2s[j][7];
                o4[j] = t7 * (pq[j] * alpha) + bq[j];
            }
            *(f32x4*)&orow[c2 * 256 + l * 4] = o4;
        }
        asm volatile("s_waitcnt lgkmcnt(0)" ::: "memory");   // t6L reuse fence (wave-local)
    };

    bf16x8 va = loadrow(n0 + 0);
    bf16x8 vb = loadrow(n0 + 1);
    __syncthreads();                       // fo0L visible to all waves (once)

    #pragma unroll
    for (int rr = 0; rr < 8; rr += 2) {
        bf16x8 vc = va;                    // consume A-slot
        if (rr + 2 < 8) va = loadrow(n0 + rr + 2);
        ROW(vc, rr);
        bf16x8 vd = vb;                    // consume B-slot
        if (rr + 3 < 8) vb = loadrow(n0 + rr + 3);
        ROW(vd, rr + 1);
    }
}

extern "C" void kernel_launch(void* const* d_in, const int* in_sizes, int n_in,
                              void* d_out, int out_size, void* d_ws, size_t ws_size,
                              hipStream_t stream) {
    const float* x     = (const float*)d_in[0];
    const float* core  = (const float*)d_in[1];
    const float* fi0   = (const float*)d_in[2];
    const float* fi1   = (const float*)d_in[3];
    const float* fi2   = (const float*)d_in[4];
    const float* fo0   = (const float*)d_in[5];
    const float* fo1   = (const float*)d_in[6];
    const float* fo2   = (const float*)d_in[7];
    const float* pds   = (const float*)d_in[8];
    const float* alpha = (const float*)d_in[9];
    const float* bias  = (const float*)d_in[10];
    const int*   perm  = (const int*)d_in[11];
    float* outp = (float*)d_out;

    char* ws = (char*)d_ws;
    unsigned int*   cb   = (unsigned int*)(ws);                   // 512 KB
    unsigned int*   t3ws = (unsigned int*)(ws + 1048576);         // 16 MB
    unsigned short* t4   = (unsigned short*)(ws + 17825792);      // 16.75 MB

    k_corebf<<<512, 256, 0, stream>>>(core, cb);
    k_t3<<<NROWS / 4, 256, 0, stream>>>(x, fi0, fi1, fi2, perm, t3ws);
    k_core<<<512, 256, 0, stream>>>((const __bf16*)t3ws, (const __bf16*)cb, t4);
    k_expand<<<512, 256, 0, stream>>>(t4, fo0, fo1, fo2, pds, alpha, bias, outp);
}

// Round 19
// 188.779 us; speedup vs baseline: 1.4493x; 1.4270x over previous
//
#include <hip/hip_runtime.h>
#include <stdint.h>

#define NROWS 16384
#define D 4096

typedef __bf16 bf16x8 __attribute__((ext_vector_type(8)));
typedef float  f32x4  __attribute__((ext_vector_type(4)));

__device__ inline unsigned short f2bf(float f) {
    unsigned u = __float_as_uint(f);
    u += 0x7fffu + ((u >> 16) & 1u);
    return (unsigned short)(u >> 16);
}

// ---------------- core -> bf16 in GEMM staging layout ----------------
__global__ __launch_bounds__(256) void k_corebf(const float* __restrict__ core,
                                                unsigned int* __restrict__ cb) {
    const int o = blockIdx.x;            // 512
    const int kp = threadIdx.x;          // bf16-pair index, k = 2*kp
    float2 v = *(const float2*)&core[o * 512 + 2 * kp];
    cb[((size_t)(kp >> 2) * 512 + o) * 4 + (kp & 3)] =
        (unsigned)f2bf(v.x) | ((unsigned)f2bf(v.y) << 16);
}

// ---------------- input contraction: 4 rows/block, dbuf pipeline ----------------
// (byte-identical to round 12 — verified)
__global__ __launch_bounds__(256, 3) void k_t3(const float* __restrict__ x,
                                               const float* __restrict__ fi0,
                                               const float* __restrict__ fi1,
                                               const float* __restrict__ fi2,
                                               const int* __restrict__ perm,
                                               unsigned int* __restrict__ t3out) {
    __shared__ float xr[2][4096];  // 32 KB, double-buffered un-permuted rows
    __shared__ float t1[2048];     //  8 KB
    __shared__ float t2[1024];     //  4 KB
    __shared__ float fac[3][128];  //  1.5 KB

    const int tid = threadIdx.x;
    const int n0 = blockIdx.x * 4;

    {
        const int h = tid & 127;
        fac[0][h] = fi0[h];
        fac[1][h] = fi1[h];
        fac[2][h] = fi2[h];
    }
    int pj[16];
    #pragma unroll
    for (int j = 0; j < 16; ++j) pj[j] = perm[j * 256 + tid];

    auto stage = [&](int b, int row) {
        const float4* src = (const float4*)(x + (size_t)row * D);
        #pragma unroll
        for (int i = 0; i < 4; ++i) {
            const int c = i * 256 + tid;
            __builtin_amdgcn_global_load_lds(
                (const __attribute__((address_space(1))) void*)(src + c),
                (__attribute__((address_space(3))) void*)(&xr[b][c * 4]),
                16, 0, 0);
        }
    };

    auto STEP3 = [&](int b) {
        float a8[8] = {0,0,0,0,0,0,0,0};
        #pragma unroll
        for (int a = 0; a < 16; ++a) {
            float v = xr[b][pj[a]];
            #pragma unroll
            for (int p = 0; p < 8; ++p) a8[p] += v * fac[0][a * 8 + p];
        }
        #pragma unroll
        for (int p = 0; p < 8; ++p) t1[p * 256 + tid] = a8[p];
    };
    auto STEP4 = [&]() {
        const int p = tid >> 5, c = (tid >> 1) & 15, qh = tid & 1;
        float a4[4] = {0,0,0,0};
        #pragma unroll
        for (int b = 0; b < 16; ++b) {
            float v = t1[p * 256 + b * 16 + c];
            #pragma unroll
            for (int qi = 0; qi < 4; ++qi) a4[qi] += v * fac[1][b * 8 + qh * 4 + qi];
        }
        #pragma unroll
        for (int qi = 0; qi < 4; ++qi) t2[p * 128 + (qh * 4 + qi) * 16 + c] = a4[qi];
    };
    auto STEP5_PACK = [&](int n) {
        const int p = tid >> 5, q = (tid >> 2) & 7, rh = tid & 3;
        float a2[2] = {0,0};
        #pragma unroll
        for (int c = 0; c < 16; ++c) {
            float v = t2[p * 128 + q * 16 + c];
            #pragma unroll
            for (int ri = 0; ri < 2; ++ri) a2[ri] += v * fac[2][c * 8 + rh * 2 + ri];
        }
        const int kt = tid >> 5, k4 = (tid >> 2) & 7, w = tid & 3;
        t3out[(((size_t)kt * 8 + k4) * NROWS + n) * 4 + w] =
            (unsigned)f2bf(a2[0]) | ((unsigned)f2bf(a2[1]) << 16);
    };

    stage(0, n0 + 0);
    stage(1, n0 + 1);

    asm volatile("s_waitcnt vmcnt(4) lgkmcnt(0)" ::: "memory");
    __builtin_amdgcn_s_barrier();
    STEP3(0);
    asm volatile("s_waitcnt lgkmcnt(0)" ::: "memory");
    __builtin_amdgcn_s_barrier();
    stage(0, n0 + 2);
    STEP4();
    asm volatile("s_waitcnt lgkmcnt(0)" ::: "memory");
    __builtin_amdgcn_s_barrier();
    STEP5_PACK(n0 + 0);

    asm volatile("s_waitcnt vmcnt(5)" ::: "memory");
    __builtin_amdgcn_s_barrier();
    STEP3(1);
    asm volatile("s_waitcnt lgkmcnt(0)" ::: "memory");
    __builtin_amdgcn_s_barrier();
    stage(1, n0 + 3);
    STEP4();
    asm volatile("s_waitcnt lgkmcnt(0)" ::: "memory");
    __builtin_amdgcn_s_barrier();
    STEP5_PACK(n0 + 1);

    asm volatile("s_waitcnt vmcnt(6)" ::: "memory");
    __builtin_amdgcn_s_barrier();
    STEP3(0);
    asm volatile("s_waitcnt lgkmcnt(0)" ::: "memory");
    __builtin_amdgcn_s_barrier();
    STEP4();
    asm volatile("s_waitcnt lgkmcnt(0)" ::: "memory");
    __builtin_amdgcn_s_barrier();
    STEP5_PACK(n0 + 2);

    asm volatile("s_waitcnt vmcnt(2)" ::: "memory");
    __builtin_amdgcn_s_barrier();
    STEP3(1);
    asm volatile("s_waitcnt lgkmcnt(0)" ::: "memory");
    __builtin_amdgcn_s_barrier();
    STEP4();
    asm volatile("s_waitcnt lgkmcnt(0)" ::: "memory");
    __builtin_amdgcn_s_barrier();
    STEP5_PACK(n0 + 3);
}

// ---------------- core GEMM: t4[n][512] = t3[n][512] @ core^T (bf16 out) ------
// (byte-identical to round 18 — transposed t4 epilogue)
__global__ __launch_bounds__(256, 2) void k_core(const __bf16* __restrict__ t3,
                                                 const __bf16* __restrict__ cb,
                                                 unsigned short* __restrict__ t4) {
    __shared__ __bf16 lA[2][8192];   // [buf][k4][row][8]  2x16 KB
    __shared__ __bf16 lB[2][8192];   //                    2x16 KB

    const int tid = threadIdx.x, lane = tid & 63, wv = tid >> 6;

    const int bid = blockIdx.x;
    const int wgid = (bid & 7) * 64 + (bid >> 3);
    const int m0 = (wgid >> 2) * 128;
    const int n0 = (wgid & 3) * 128;
    const int wm = wv >> 1, wn = wv & 1;
    const int l15 = lane & 15, l4 = lane >> 4;

    auto stage = [&](int b, int kt) {
        #pragma unroll
        for (int i = 0; i < 4; ++i) {
            const int c = i * 256 + tid;
            const int k4 = c >> 7, r = c & 127;
            const __bf16* ga = t3 + ((size_t)(kt * 8 + k4) * NROWS + m0 + r) * 8;
            __builtin_amdgcn_global_load_lds(
                (const __attribute__((address_space(1))) void*)ga,
                (__attribute__((address_space(3))) void*)(&lA[b][(size_t)c * 8]),
                16, 0, 0);
            const __bf16* gb = cb + ((size_t)(kt * 8 + k4) * 512 + n0 + r) * 8;
            __builtin_amdgcn_global_load_lds(
                (const __attribute__((address_space(1))) void*)gb,
                (__attribute__((address_space(3))) void*)(&lB[b][(size_t)c * 8]),
                16, 0, 0);
        }
    };

    f32x4 acc[4][4] = {};

    auto compute = [&](int cur) {
        #pragma unroll
        for (int kk = 0; kk < 2; ++kk) {
            const int k4f = kk * 4 + l4;
            bf16x8 af[4], bfr[4];
            #pragma unroll
            for (int mt = 0; mt < 4; ++mt)
                af[mt] = *(const bf16x8*)&lA[cur][(k4f * 128 + wm * 64 + mt * 16 + l15) * 8];
            #pragma unroll
            for (int nt = 0; nt < 4; ++nt)
                bfr[nt] = *(const bf16x8*)&lB[cur][(k4f * 128 + wn * 64 + nt * 16 + l15) * 8];
            #pragma unroll
            for (int mt = 0; mt < 4; ++mt)
                #pragma unroll
                for (int nt = 0; nt < 4; ++nt)
                    acc[mt][nt] = __builtin_amdgcn_mfma_f32_16x16x32_bf16(
                        af[mt], bfr[nt], acc[mt][nt], 0, 0, 0);
        }
    };

    stage(0, 0);
    stage(1, 1);
    #pragma unroll 1
    for (int kt = 0; kt < 8; ++kt) {
        if (kt < 7) asm volatile("s_waitcnt vmcnt(8)" ::: "memory");
        else        asm volatile("s_waitcnt vmcnt(0)" ::: "memory");
        __builtin_amdgcn_s_barrier();
        __builtin_amdgcn_s_setprio(1);
        compute(kt & 1);
        __builtin_amdgcn_s_setprio(0);
        __builtin_amdgcn_s_barrier();
        if (kt < 6) stage(kt & 1, kt + 2);
    }

    // epilogue: pack bf16 into TRANSPOSED per-row layout
    #pragma unroll
    for (int nt = 0; nt < 4; ++nt) {
        const int col = n0 + wn * 64 + nt * 16 + l15;     // o index
        const int oo = (col & 63) * 8 + (col >> 6);       // transposed offset
        #pragma unroll
        for (int mt = 0; mt < 4; ++mt) {
            const int row = m0 + wm * 64 + mt * 16 + l4 * 4;
            #pragma unroll
            for (int j = 0; j < 4; ++j)
                t4[(size_t)(row + j) * 512 + oo] = f2bf(acc[mt][nt][j]);
        }
    }
}

// ---------------- output expansion v5: 2 rows/wave, 2048 blocks ----------------
// v4 fixes: (1) grid 2048 (8 blocks/CU available; LDS 52.5 KB -> 3 resident,
// 12 waves/CU) — v4's 512-block grid capped at 2 blocks/CU regardless of LDS;
// (2) straight-line 2-row body (no loop, no full-unroll codegen pathology).
// t4 read stays the coalesced transposed 16 B/lane register load.
__global__ __launch_bounds__(256, 3) void k_expand(const unsigned short* __restrict__ t4,
                                                   const float* __restrict__ fo0,
                                                   const float* __restrict__ fo1,
                                                   const float* __restrict__ fo2,
                                                   const float* __restrict__ pds,
                                                   const float* __restrict__ alphap,
                                                   const float* __restrict__ bias,
                                                   float* __restrict__ out) {
    __shared__ float  t5L[4][1024];     // 16 KB  [w][X*64 + z*8 + y]
    __shared__ float  t6L[4][2304];     // 36 KB  [w][(X*16+Y)*9 + z]
    __shared__ float  fo0L[128];        // 0.5 KB

    const int tid = threadIdx.x, w = tid >> 6, l = tid & 63;
    const int n0 = blockIdx.x * 8 + w * 2;     // 2 rows per wave
    const int ly = l >> 3, lz = l & 7;         // (y, z) role in phase A/B
    const int lq = l & 3, lx = l >> 2;         // (Z-quad, XY-sub) role in phase C

    if (tid < 128) fo0L[tid] = fo0[tid];
    const float alpha = alphap[0];

    float fo1f[2][8];                      // fo1[(ly + 8h)*8 + y]
    #pragma unroll
    for (int h = 0; h < 2; ++h) {
        f32x4 a = *(const f32x4*)&fo1[(h * 8 + ly) * 8];
        f32x4 b = *(const f32x4*)&fo1[(h * 8 + ly) * 8 + 4];
        #pragma unroll
        for (int j = 0; j < 4; ++j) { fo1f[h][j] = a[j]; fo1f[h][4 + j] = b[j]; }
    }
    float fo2s[4][8];                      // fo2[(lq*4+j)*8 + z] slice
    #pragma unroll
    for (int j = 0; j < 4; ++j) {
        f32x4 a = *(const f32x4*)&fo2[(lq * 4 + j) * 8];
        f32x4 b = *(const f32x4*)&fo2[(lq * 4 + j) * 8 + 4];
        #pragma unroll
        for (int zz = 0; zz < 4; ++zz) { fo2s[j][zz] = a[zz]; fo2s[j][4 + zz] = b[zz]; }
    }

    // lane l owns yz = l: 8 contiguous bf16 at t4[n*512 + l*8] (transposed layout)
    bf16x8 va = *(const bf16x8*)(t4 + (size_t)(n0 + 0) * 512 + l * 8);
    bf16x8 vb = *(const bf16x8*)(t4 + (size_t)(n0 + 1) * 512 + l * 8);

    auto ROW = [&](bf16x8 vcur, int r) {
        // ---- phase A: rv[x] from registers; t5[X][lz][ly] ----
        float rv[8];
        #pragma unroll
        for (int xx = 0; xx < 8; ++xx) rv[xx] = (float)vcur[xx];
        #pragma unroll
        for (int X = 0; X < 16; ++X) {
            f32x4 f0 = *(const f32x4*)&fo0L[X * 8];
            f32x4 f1 = *(const f32x4*)&fo0L[X * 8 + 4];
            float s = rv[0] * f0[0] + rv[1] * f0[1] + rv[2] * f0[2] + rv[3] * f0[3]
                    + rv[4] * f1[0] + rv[5] * f1[1] + rv[6] * f1[2] + rv[7] * f1[3];
            t5L[w][X * 64 + lz * 8 + ly] = s;
        }
        asm volatile("s_waitcnt lgkmcnt(0)" ::: "memory");

        // ---- phase B: lane (Y2=ly, z=lz); t6[X][Y][lz] for Y=ly, ly+8 ----
        #pragma unroll
        for (int X = 0; X < 16; ++X) {
            f32x4 u0 = *(const f32x4*)&t5L[w][X * 64 + lz * 8];
            f32x4 u1 = *(const f32x4*)&t5L[w][X * 64 + lz * 8 + 4];
            float a0 = u0[0] * fo1f[0][0] + u0[1] * fo1f[0][1] + u0[2] * fo1f[0][2] + u0[3] * fo1f[0][3]
                     + u1[0] * fo1f[0][4] + u1[1] * fo1f[0][5] + u1[2] * fo1f[0][6] + u1[3] * fo1f[0][7];
            float a1 = u0[0] * fo1f[1][0] + u0[1] * fo1f[1][1] + u0[2] * fo1f[1][2] + u0[3] * fo1f[1][3]
                     + u1[0] * fo1f[1][4] + u1[1] * fo1f[1][5] + u1[2] * fo1f[1][6] + u1[3] * fo1f[1][7];
            t6L[w][(X * 16 + ly) * 9 + lz]     = a0;
            t6L[w][(X * 16 + ly + 8) * 9 + lz] = a1;
        }
        asm volatile("s_waitcnt lgkmcnt(0)" ::: "memory");

        // ---- phase C: lane-contiguous loads/stores ----
        float* orow = out + (size_t)(n0 + r) * 4096;
        #pragma unroll
        for (int c2 = 0; c2 < 16; ++c2) {
            const int XY = c2 * 16 + lx;
            f32x4 pq = *(const f32x4*)&pds[c2 * 256 + l * 4];
            f32x4 bq = *(const f32x4*)&bias[c2 * 256 + l * 4];
            float tv[8];
            #pragma unroll
            for (int zz = 0; zz < 8; ++zz) tv[zz] = t6L[w][XY * 9 + zz];
            f32x4 o4;
            #pragma unroll
            for (int j = 0; j < 4; ++j) {
                float t7 = tv[0] * fo2s[j][0] + tv[1] * fo2s[j][1]
                         + tv[2] * fo2s[j][2] + tv[3] * fo2s[j][3]
                         + tv[4] * fo2s[j][4] + tv[5] * fo2s[j][5]
                         + tv[6] * fo2s[j][6] + tv[7] * fo2s[j][7];
                o4[j] = t7 * (pq[j] * alpha) + bq[j];
            }
            *(f32x4*)&orow[c2 * 256 + l * 4] = o4;
        }
        asm volatile("s_waitcnt lgkmcnt(0)" ::: "memory");   // t5/t6 reuse fence (wave-local)
    };

    __syncthreads();                       // fo0L visible to all waves (once)
    ROW(va, 0);
    ROW(vb, 1);
}

extern "C" void kernel_launch(void* const* d_in, const int* in_sizes, int n_in,
                              void* d_out, int out_size, void* d_ws, size_t ws_size,
                              hipStream_t stream) {
    const float* x     = (const float*)d_in[0];
    const float* core  = (const float*)d_in[1];
    const float* fi0   = (const float*)d_in[2];
    const float* fi1   = (const float*)d_in[3];
    const float* fi2   = (const float*)d_in[4];
    const float* fo0   = (const float*)d_in[5];
    const float* fo1   = (const float*)d_in[6];
    const float* fo2   = (const float*)d_in[7];
    const float* pds   = (const float*)d_in[8];
    const float* alpha = (const float*)d_in[9];
    const float* bias  = (const float*)d_in[10];
    const int*   perm  = (const int*)d_in[11];
    float* outp = (float*)d_out;

    char* ws = (char*)d_ws;
    unsigned int*   cb   = (unsigned int*)(ws);                   // 512 KB
    unsigned int*   t3ws = (unsigned int*)(ws + 1048576);         // 16 MB
    unsigned short* t4   = (unsigned short*)(ws + 17825792);      // 16.75 MB

    k_corebf<<<512, 256, 0, stream>>>(core, cb);
    k_t3<<<NROWS / 4, 256, 0, stream>>>(x, fi0, fi1, fi2, perm, t3ws);
    k_core<<<512, 256, 0, stream>>>((const __bf16*)t3ws, (const __bf16*)cb, t4);
    k_expand<<<2048, 256, 0, stream>>>(t4, fo0, fo1, fo2, pds, alpha, bias, outp);
}

// Round 20
// 167.755 us; speedup vs baseline: 1.6310x; 1.1253x over previous
//
#include <hip/hip_runtime.h>
#include <stdint.h>

#define NROWS 16384
#define D 4096

typedef __bf16 bf16x8 __attribute__((ext_vector_type(8)));
typedef float  f32x4  __attribute__((ext_vector_type(4)));

__device__ inline unsigned short f2bf(float f) {
    unsigned u = __float_as_uint(f);
    u += 0x7fffu + ((u >> 16) & 1u);
    return (unsigned short)(u >> 16);
}

// ---------------- core -> bf16 in GEMM staging layout ----------------
__global__ __launch_bounds__(256) void k_corebf(const float* __restrict__ core,
                                                unsigned int* __restrict__ cb) {
    const int o = blockIdx.x;            // 512
    const int kp = threadIdx.x;          // bf16-pair index, k = 2*kp
    float2 v = *(const float2*)&core[o * 512 + 2 * kp];
    cb[((size_t)(kp >> 2) * 512 + o) * 4 + (kp & 3)] =
        (unsigned)f2bf(v.x) | ((unsigned)f2bf(v.y) << 16);
}

// ---------------- input contraction v2: 1 row/block, 5 blocks/CU ----------------
// Round-12's phase bodies, but single-row blocks: no in-block row pipeline —
// 5 resident blocks/CU provide the latency overlap instead (m114 mechanism);
// 3 barriers/row instead of 3+gates; 29.5 KB LDS.
__global__ __launch_bounds__(256, 5) void k_t3(const float* __restrict__ x,
                                               const float* __restrict__ fi0,
                                               const float* __restrict__ fi1,
                                               const float* __restrict__ fi2,
                                               const int* __restrict__ perm,
                                               unsigned int* __restrict__ t3out) {
    __shared__ float xr[4096];     // 16 KB
    __shared__ float t1[2048];     //  8 KB
    __shared__ float t2[1024];     //  4 KB
    __shared__ float fac[3][128];  //  1.5 KB

    const int tid = threadIdx.x;
    const int n = blockIdx.x;

    {
        const int h = tid & 127;
        fac[0][h] = fi0[h];
        fac[1][h] = fi1[h];
        fac[2][h] = fi2[h];
    }
    int pj[16];
    #pragma unroll
    for (int j = 0; j < 16; ++j) pj[j] = perm[j * 256 + tid];

    // stage the row linearly into xr: 4 x gload_lds 16 B, coalesced
    {
        const float4* src = (const float4*)(x + (size_t)n * D);
        #pragma unroll
        for (int i = 0; i < 4; ++i) {
            const int c = i * 256 + tid;
            __builtin_amdgcn_global_load_lds(
                (const __attribute__((address_space(1))) void*)(src + c),
                (__attribute__((address_space(3))) void*)(&xr[c * 4]),
                16, 0, 0);
        }
    }
    asm volatile("s_waitcnt vmcnt(0) lgkmcnt(0)" ::: "memory");
    __builtin_amdgcn_s_barrier();

    // STEP3: t1[p][bc] = sum_a xr[perm[a*256+bc]] * fi0[a,p]
    {
        float a8[8] = {0,0,0,0,0,0,0,0};
        #pragma unroll
        for (int a = 0; a < 16; ++a) {
            float v = xr[pj[a]];
            #pragma unroll
            for (int p = 0; p < 8; ++p) a8[p] += v * fac[0][a * 8 + p];
        }
        #pragma unroll
        for (int p = 0; p < 8; ++p) t1[p * 256 + tid] = a8[p];
    }
    asm volatile("s_waitcnt lgkmcnt(0)" ::: "memory");
    __builtin_amdgcn_s_barrier();

    // STEP4: t2[p][q][c] = sum_b t1[p][b*16+c] * fi1[b,q]
    {
        const int p = tid >> 5, c = (tid >> 1) & 15, qh = tid & 1;
        float a4[4] = {0,0,0,0};
        #pragma unroll
        for (int b = 0; b < 16; ++b) {
            float v = t1[p * 256 + b * 16 + c];
            #pragma unroll
            for (int qi = 0; qi < 4; ++qi) a4[qi] += v * fac[1][b * 8 + qh * 4 + qi];
        }
        #pragma unroll
        for (int qi = 0; qi < 4; ++qi) t2[p * 128 + (qh * 4 + qi) * 16 + c] = a4[qi];
    }
    asm volatile("s_waitcnt lgkmcnt(0)" ::: "memory");
    __builtin_amdgcn_s_barrier();

    // STEP5: t3[p][q][rr] = sum_c t2[p][q][c] * fi2[c,rr]; pack + store
    {
        const int p = tid >> 5, q = (tid >> 2) & 7, rh = tid & 3;
        float a2[2] = {0,0};
        #pragma unroll
        for (int c = 0; c < 16; ++c) {
            float v = t2[p * 128 + q * 16 + c];
            #pragma unroll
            for (int ri = 0; ri < 2; ++ri) a2[ri] += v * fac[2][c * 8 + rh * 2 + ri];
        }
        const int kt = tid >> 5, k4 = (tid >> 2) & 7, w = tid & 3;
        t3out[(((size_t)kt * 8 + k4) * NROWS + n) * 4 + w] =
            (unsigned)f2bf(a2[0]) | ((unsigned)f2bf(a2[1]) << 16);
    }
}

// ---------------- core GEMM: t4[n][512] = t3[n][512] @ core^T (bf16 out) ------
// (byte-identical to round 12/16 — verified; row-major t4)
__global__ __launch_bounds__(256, 2) void k_core(const __bf16* __restrict__ t3,
                                                 const __bf16* __restrict__ cb,
                                                 unsigned short* __restrict__ t4) {
    __shared__ __bf16 lA[2][8192];   // [buf][k4][row][8]  2x16 KB
    __shared__ __bf16 lB[2][8192];   //                    2x16 KB

    const int tid = threadIdx.x, lane = tid & 63, wv = tid >> 6;

    const int bid = blockIdx.x;
    const int wgid = (bid & 7) * 64 + (bid >> 3);
    const int m0 = (wgid >> 2) * 128;
    const int n0 = (wgid & 3) * 128;
    const int wm = wv >> 1, wn = wv & 1;
    const int l15 = lane & 15, l4 = lane >> 4;

    auto stage = [&](int b, int kt) {
        #pragma unroll
        for (int i = 0; i < 4; ++i) {
            const int c = i * 256 + tid;
            const int k4 = c >> 7, r = c & 127;
            const __bf16* ga = t3 + ((size_t)(kt * 8 + k4) * NROWS + m0 + r) * 8;
            __builtin_amdgcn_global_load_lds(
                (const __attribute__((address_space(1))) void*)ga,
                (__attribute__((address_space(3))) void*)(&lA[b][(size_t)c * 8]),
                16, 0, 0);
            const __bf16* gb = cb + ((size_t)(kt * 8 + k4) * 512 + n0 + r) * 8;
            __builtin_amdgcn_global_load_lds(
                (const __attribute__((address_space(1))) void*)gb,
                (__attribute__((address_space(3))) void*)(&lB[b][(size_t)c * 8]),
                16, 0, 0);
        }
    };

    f32x4 acc[4][4] = {};

    auto compute = [&](int cur) {
        #pragma unroll
        for (int kk = 0; kk < 2; ++kk) {
            const int k4f = kk * 4 + l4;
            bf16x8 af[4], bfr[4];
            #pragma unroll
            for (int mt = 0; mt < 4; ++mt)
                af[mt] = *(const bf16x8*)&lA[cur][(k4f * 128 + wm * 64 + mt * 16 + l15) * 8];
            #pragma unroll
            for (int nt = 0; nt < 4; ++nt)
                bfr[nt] = *(const bf16x8*)&lB[cur][(k4f * 128 + wn * 64 + nt * 16 + l15) * 8];
            #pragma unroll
            for (int mt = 0; mt < 4; ++mt)
                #pragma unroll
                for (int nt = 0; nt < 4; ++nt)
                    acc[mt][nt] = __builtin_amdgcn_mfma_f32_16x16x32_bf16(
                        af[mt], bfr[nt], acc[mt][nt], 0, 0, 0);
        }
    };

    stage(0, 0);
    stage(1, 1);
    #pragma unroll 1
    for (int kt = 0; kt < 8; ++kt) {
        if (kt < 7) asm volatile("s_waitcnt vmcnt(8)" ::: "memory");
        else        asm volatile("s_waitcnt vmcnt(0)" ::: "memory");
        __builtin_amdgcn_s_barrier();
        __builtin_amdgcn_s_setprio(1);
        compute(kt & 1);
        __builtin_amdgcn_s_setprio(0);
        __builtin_amdgcn_s_barrier();
        if (kt < 6) stage(kt & 1, kt + 2);
    }

    #pragma unroll
    for (int nt = 0; nt < 4; ++nt) {
        const int col = n0 + wn * 64 + nt * 16 + l15;
        #pragma unroll
        for (int mt = 0; mt < 4; ++mt) {
            const int row = m0 + wm * 64 + mt * 16 + l4 * 4;
            #pragma unroll
            for (int j = 0; j < 4; ++j)
                t4[(size_t)(row + j) * 512 + col] = f2bf(acc[mt][nt][j]);
        }
    }
}

// ---------------- output expansion v3: wave-per-row, coalesced stores ----------
// (byte-identical to round 16 — the 174.0 configuration's expand)
__global__ __launch_bounds__(256, 2) void k_expand(const unsigned short* __restrict__ t4,
                                                   const float* __restrict__ fo0,
                                                   const float* __restrict__ fo1,
                                                   const float* __restrict__ fo2,
                                                   const float* __restrict__ pds,
                                                   const float* __restrict__ alphap,
                                                   const float* __restrict__ bias,
                                                   float* __restrict__ out) {
    __shared__ __bf16 t4L[4][2][512];   //  8 KB  per-wave dbuf t4 rows
    __shared__ float  t5L[4][1024];     // 16 KB  [w][X*64 + z*8 + y]
    __shared__ float  t6L[4][2304];     // 36 KB  [w][(X*16+Y)*9 + z]
    __shared__ float  fo0L[128];        // 0.5 KB

    const int tid = threadIdx.x, w = tid >> 6, l = tid & 63;
    const int n0 = blockIdx.x * 32 + w * 8;
    const int ly = l >> 3, lz = l & 7;     // (y, z) role in phase A/B
    const int lq = l & 3, lx = l >> 2;     // (Z-quad, XY-sub) role in phase C

    if (tid < 128) fo0L[tid] = fo0[tid];
    const float alpha = alphap[0];

    float fo1f[2][8];                      // fo1[(ly + 8h)*8 + y]
    #pragma unroll
    for (int h = 0; h < 2; ++h) {
        f32x4 a = *(const f32x4*)&fo1[(h * 8 + ly) * 8];
        f32x4 b = *(const f32x4*)&fo1[(h * 8 + ly) * 8 + 4];
        #pragma unroll
        for (int j = 0; j < 4; ++j) { fo1f[h][j] = a[j]; fo1f[h][4 + j] = b[j]; }
    }
    float fo2s[4][8];                      // fo2[(lq*4+j)*8 + z] slice
    #pragma unroll
    for (int j = 0; j < 4; ++j) {
        f32x4 a = *(const f32x4*)&fo2[(lq * 4 + j) * 8];
        f32x4 b = *(const f32x4*)&fo2[(lq * 4 + j) * 8 + 4];
        #pragma unroll
        for (int zz = 0; zz < 4; ++zz) { fo2s[j][zz] = a[zz]; fo2s[j][4 + zz] = b[zz]; }
    }

    auto stage = [&](int b, int n) {
        const unsigned short* src = t4 + (size_t)n * 512 + l * 8;
        __builtin_amdgcn_global_load_lds(
            (const __attribute__((address_space(1))) void*)src,
            (__attribute__((address_space(3))) void*)(&t4L[w][b][l * 8]),
            16, 0, 0);
    };

    stage(0, n0);
    asm volatile("s_waitcnt vmcnt(0) lgkmcnt(0)" ::: "memory");
    __syncthreads();                       // fo0L + first t4 row visible

    #pragma unroll 1
    for (int r = 0; r < 8; ++r) {
        const int b = r & 1;
        if (r) asm volatile("s_waitcnt vmcnt(48)" ::: "memory");  // stage(r) done

        // ---- phase A: rv[x] = t4[x*64+l]; t5[X][lz][ly] ----
        float rv[8];
        #pragma unroll
        for (int xx = 0; xx < 8; ++xx)
            rv[xx] = (float)t4L[w][b][xx * 64 + l];
        if (r + 1 < 8) stage(b ^ 1, n0 + r + 1);   // prefetch next row
        #pragma unroll
        for (int X = 0; X < 16; ++X) {
            f32x4 f0 = *(const f32x4*)&fo0L[X * 8];
            f32x4 f1 = *(const f32x4*)&fo0L[X * 8 + 4];
            float s = rv[0] * f0[0] + rv[1] * f0[1] + rv[2] * f0[2] + rv[3] * f0[3]
                    + rv[4] * f1[0] + rv[5] * f1[1] + rv[6] * f1[2] + rv[7] * f1[3];
            t5L[w][X * 64 + lz * 8 + ly] = s;
        }
        asm volatile("s_waitcnt lgkmcnt(0)" ::: "memory");

        // ---- phase B: lane (Y2=ly, z=lz); t6[X][Y][lz] for Y=ly, ly+8 ----
        #pragma unroll
        for (int X = 0; X < 16; ++X) {
            f32x4 u0 = *(const f32x4*)&t5L[w][X * 64 + lz * 8];
            f32x4 u1 = *(const f32x4*)&t5L[w][X * 64 + lz * 8 + 4];
            float a0 = u0[0] * fo1f[0][0] + u0[1] * fo1f[0][1] + u0[2] * fo1f[0][2] + u0[3] * fo1f[0][3]
                     + u1[0] * fo1f[0][4] + u1[1] * fo1f[0][5] + u1[2] * fo1f[0][6] + u1[3] * fo1f[0][7];
            float a1 = u0[0] * fo1f[1][0] + u0[1] * fo1f[1][1] + u0[2] * fo1f[1][2] + u0[3] * fo1f[1][3]
                     + u1[0] * fo1f[1][4] + u1[1] * fo1f[1][5] + u1[2] * fo1f[1][6] + u1[3] * fo1f[1][7];
            t6L[w][(X * 16 + ly) * 9 + lz]     = a0;
            t6L[w][(X * 16 + ly + 8) * 9 + lz] = a1;
        }
        asm volatile("s_waitcnt lgkmcnt(0)" ::: "memory");

        // ---- phase C: lane-contiguous loads/stores ----
        float* orow = out + (size_t)(n0 + r) * 4096;
        #pragma unroll
        for (int c2 = 0; c2 < 16; ++c2) {
            const int XY = c2 * 16 + lx;
            f32x4 pq = *(const f32x4*)&pds[c2 * 256 + l * 4];
            f32x4 bq = *(const f32x4*)&bias[c2 * 256 + l * 4];
            float tv[8];
            #pragma unroll
            for (int zz = 0; zz < 8; ++zz) tv[zz] = t6L[w][XY * 9 + zz];
            f32x4 o4;
            #pragma unroll
            for (int j = 0; j < 4; ++j) {
                float t7 = tv[0] * fo2s[j][0] + tv[1] * fo2s[j][1]
                         + tv[2] * fo2s[j][2] + tv[3] * fo2s[j][3]
                         + tv[4] * fo2s[j][4] + tv[5] * fo2s[j][5]
                         + tv[6] * fo2s[j][6] + tv[7] * fo2s[j][7];
                o4[j] = t7 * (pq[j] * alpha) + bq[j];
            }
            *(f32x4*)&orow[c2 * 256 + l * 4] = o4;
        }
    }
}

extern "C" void kernel_launch(void* const* d_in, const int* in_sizes, int n_in,
                              void* d_out, int out_size, void* d_ws, size_t ws_size,
                              hipStream_t stream) {
    const float* x     = (const float*)d_in[0];
    const float* core  = (const float*)d_in[1];
    const float* fi0   = (const float*)d_in[2];
    const float* fi1   = (const float*)d_in[3];
    const float* fi2   = (const float*)d_in[4];
    const float* fo0   = (const float*)d_in[5];
    const float* fo1   = (const float*)d_in[6];
    const float* fo2   = (const float*)d_in[7];
    const float* pds   = (const float*)d_in[8];
    const float* alpha = (const float*)d_in[9];
    const float* bias  = (const float*)d_in[10];
    const int*   perm  = (const int*)d_in[11];
    float* outp = (float*)d_out;

    char* ws = (char*)d_ws;
    unsigned int*   cb   = (unsigned int*)(ws);                   // 512 KB
    unsigned int*   t3ws = (unsigned int*)(ws + 1048576);         // 16 MB
    unsigned short* t4   = (unsigned short*)(ws + 17825792);      // 16.75 MB

    k_corebf<<<512, 256, 0, stream>>>(core, cb);
    k_t3<<<NROWS, 256, 0, stream>>>(x, fi0, fi1, fi2, perm, t3ws);
    k_core<<<512, 256, 0, stream>>>((const __bf16*)t3ws, (const __bf16*)cb, t4);
    k_expand<<<512, 256, 0, stream>>>(t4, fo0, fo1, fo2, pds, alpha, bias, outp);
}

// Round 21
// 163.178 us; speedup vs baseline: 1.6767x; 1.0280x over previous
//
#include <hip/hip_runtime.h>
#include <stdint.h>

#define NROWS 16384
#define D 4096

typedef __bf16 bf16x8 __attribute__((ext_vector_type(8)));
typedef float  f32x4  __attribute__((ext_vector_type(4)));

__device__ inline unsigned short f2bf(float f) {
    unsigned u = __float_as_uint(f);
    u += 0x7fffu + ((u >> 16) & 1u);
    return (unsigned short)(u >> 16);
}

// ---------------- core -> bf16 in GEMM staging layout ----------------
__global__ __launch_bounds__(256) void k_corebf(const float* __restrict__ core,
                                                unsigned int* __restrict__ cb) {
    const int o = blockIdx.x;            // 512
    const int kp = threadIdx.x;          // bf16-pair index, k = 2*kp
    float2 v = *(const float2*)&core[o * 512 + 2 * kp];
    cb[((size_t)(kp >> 2) * 512 + o) * 4 + (kp & 3)] =
        (unsigned)f2bf(v.x) | ((unsigned)f2bf(v.y) << 16);
}

// ---------------- input contraction v2: 1 row/block, 5 blocks/CU ----------------
// (byte-identical to round 20 — verified, 167.8 config)
__global__ __launch_bounds__(256, 5) void k_t3(const float* __restrict__ x,
                                               const float* __restrict__ fi0,
                                               const float* __restrict__ fi1,
                                               const float* __restrict__ fi2,
                                               const int* __restrict__ perm,
                                               unsigned int* __restrict__ t3out) {
    __shared__ float xr[4096];     // 16 KB
    __shared__ float t1[2048];     //  8 KB
    __shared__ float t2[1024];     //  4 KB
    __shared__ float fac[3][128];  //  1.5 KB

    const int tid = threadIdx.x;
    const int n = blockIdx.x;

    {
        const int h = tid & 127;
        fac[0][h] = fi0[h];
        fac[1][h] = fi1[h];
        fac[2][h] = fi2[h];
    }
    int pj[16];
    #pragma unroll
    for (int j = 0; j < 16; ++j) pj[j] = perm[j * 256 + tid];

    {
        const float4* src = (const float4*)(x + (size_t)n * D);
        #pragma unroll
        for (int i = 0; i < 4; ++i) {
            const int c = i * 256 + tid;
            __builtin_amdgcn_global_load_lds(
                (const __attribute__((address_space(1))) void*)(src + c),
                (__attribute__((address_space(3))) void*)(&xr[c * 4]),
                16, 0, 0);
        }
    }
    asm volatile("s_waitcnt vmcnt(0) lgkmcnt(0)" ::: "memory");
    __builtin_amdgcn_s_barrier();

    {
        float a8[8] = {0,0,0,0,0,0,0,0};
        #pragma unroll
        for (int a = 0; a < 16; ++a) {
            float v = xr[pj[a]];
            #pragma unroll
            for (int p = 0; p < 8; ++p) a8[p] += v * fac[0][a * 8 + p];
        }
        #pragma unroll
        for (int p = 0; p < 8; ++p) t1[p * 256 + tid] = a8[p];
    }
    asm volatile("s_waitcnt lgkmcnt(0)" ::: "memory");
    __builtin_amdgcn_s_barrier();

    {
        const int p = tid >> 5, c = (tid >> 1) & 15, qh = tid & 1;
        float a4[4] = {0,0,0,0};
        #pragma unroll
        for (int b = 0; b < 16; ++b) {
            float v = t1[p * 256 + b * 16 + c];
            #pragma unroll
            for (int qi = 0; qi < 4; ++qi) a4[qi] += v * fac[1][b * 8 + qh * 4 + qi];
        }
        #pragma unroll
        for (int qi = 0; qi < 4; ++qi) t2[p * 128 + (qh * 4 + qi) * 16 + c] = a4[qi];
    }
    asm volatile("s_waitcnt lgkmcnt(0)" ::: "memory");
    __builtin_amdgcn_s_barrier();

    {
        const int p = tid >> 5, q = (tid >> 2) & 7, rh = tid & 3;
        float a2[2] = {0,0};
        #pragma unroll
        for (int c = 0; c < 16; ++c) {
            float v = t2[p * 128 + q * 16 + c];
            #pragma unroll
            for (int ri = 0; ri < 2; ++ri) a2[ri] += v * fac[2][c * 8 + rh * 2 + ri];
        }
        const int kt = tid >> 5, k4 = (tid >> 2) & 7, w = tid & 3;
        t3out[(((size_t)kt * 8 + k4) * NROWS + n) * 4 + w] =
            (unsigned)f2bf(a2[0]) | ((unsigned)f2bf(a2[1]) << 16);
    }
}

// ---------------- core GEMM: t4[n][512] = t3[n][512] @ core^T (bf16 out) ------
// (byte-identical to round 12/16/20 — verified; row-major t4)
__global__ __launch_bounds__(256, 2) void k_core(const __bf16* __restrict__ t3,
                                                 const __bf16* __restrict__ cb,
                                                 unsigned short* __restrict__ t4) {
    __shared__ __bf16 lA[2][8192];   // [buf][k4][row][8]  2x16 KB
    __shared__ __bf16 lB[2][8192];   //                    2x16 KB

    const int tid = threadIdx.x, lane = tid & 63, wv = tid >> 6;

    const int bid = blockIdx.x;
    const int wgid = (bid & 7) * 64 + (bid >> 3);
    const int m0 = (wgid >> 2) * 128;
    const int n0 = (wgid & 3) * 128;
    const int wm = wv >> 1, wn = wv & 1;
    const int l15 = lane & 15, l4 = lane >> 4;

    auto stage = [&](int b, int kt) {
        #pragma unroll
        for (int i = 0; i < 4; ++i) {
            const int c = i * 256 + tid;
            const int k4 = c >> 7, r = c & 127;
            const __bf16* ga = t3 + ((size_t)(kt * 8 + k4) * NROWS + m0 + r) * 8;
            __builtin_amdgcn_global_load_lds(
                (const __attribute__((address_space(1))) void*)ga,
                (__attribute__((address_space(3))) void*)(&lA[b][(size_t)c * 8]),
                16, 0, 0);
            const __bf16* gb = cb + ((size_t)(kt * 8 + k4) * 512 + n0 + r) * 8;
            __builtin_amdgcn_global_load_lds(
                (const __attribute__((address_space(1))) void*)gb,
                (__attribute__((address_space(3))) void*)(&lB[b][(size_t)c * 8]),
                16, 0, 0);
        }
    };

    f32x4 acc[4][4] = {};

    auto compute = [&](int cur) {
        #pragma unroll
        for (int kk = 0; kk < 2; ++kk) {
            const int k4f = kk * 4 + l4;
            bf16x8 af[4], bfr[4];
            #pragma unroll
            for (int mt = 0; mt < 4; ++mt)
                af[mt] = *(const bf16x8*)&lA[cur][(k4f * 128 + wm * 64 + mt * 16 + l15) * 8];
            #pragma unroll
            for (int nt = 0; nt < 4; ++nt)
                bfr[nt] = *(const bf16x8*)&lB[cur][(k4f * 128 + wn * 64 + nt * 16 + l15) * 8];
            #pragma unroll
            for (int mt = 0; mt < 4; ++mt)
                #pragma unroll
                for (int nt = 0; nt < 4; ++nt)
                    acc[mt][nt] = __builtin_amdgcn_mfma_f32_16x16x32_bf16(
                        af[mt], bfr[nt], acc[mt][nt], 0, 0, 0);
        }
    };

    stage(0, 0);
    stage(1, 1);
    #pragma unroll 1
    for (int kt = 0; kt < 8; ++kt) {
        if (kt < 7) asm volatile("s_waitcnt vmcnt(8)" ::: "memory");
        else        asm volatile("s_waitcnt vmcnt(0)" ::: "memory");
        __builtin_amdgcn_s_barrier();
        __builtin_amdgcn_s_setprio(1);
        compute(kt & 1);
        __builtin_amdgcn_s_setprio(0);
        __builtin_amdgcn_s_barrier();
        if (kt < 6) stage(kt & 1, kt + 2);
    }

    #pragma unroll
    for (int nt = 0; nt < 4; ++nt) {
        const int col = n0 + wn * 64 + nt * 16 + l15;
        #pragma unroll
        for (int mt = 0; mt < 4; ++mt) {
            const int row = m0 + wm * 64 + mt * 16 + l4 * 4;
            #pragma unroll
            for (int j = 0; j < 4; ++j)
                t4[(size_t)(row + j) * 512 + col] = f2bf(acc[mt][nt][j]);
        }
    }
}

// ---------------- output expansion v6: v3 + pds/bias hoisted to registers ------
// Phase-C constants (pq = pds*alpha, bq = bias) are row-invariant per lane:
// load ONCE before the row loop (32 f32x4 = 128 VGPR; 84+128=212 <= 256 at
// 2 waves/SIMD) instead of 32 loads/row. Per-row VMEM drops 49 -> 17
// (1 stage + 16 stores) -> gate vmcnt(16). Everything else = round-16 v3.
__global__ __launch_bounds__(256, 2) void k_expand(const unsigned short* __restrict__ t4,
                                                   const float* __restrict__ fo0,
                                                   const float* __restrict__ fo1,
                                                   const float* __restrict__ fo2,
                                                   const float* __restrict__ pds,
                                                   const float* __restrict__ alphap,
                                                   const float* __restrict__ bias,
                                                   float* __restrict__ out) {
    __shared__ __bf16 t4L[4][2][512];   //  8 KB  per-wave dbuf t4 rows
    __shared__ float  t5L[4][1024];     // 16 KB  [w][X*64 + z*8 + y]
    __shared__ float  t6L[4][2304];     // 36 KB  [w][(X*16+Y)*9 + z]
    __shared__ float  fo0L[128];        // 0.5 KB

    const int tid = threadIdx.x, w = tid >> 6, l = tid & 63;
    const int n0 = blockIdx.x * 32 + w * 8;
    const int ly = l >> 3, lz = l & 7;     // (y, z) role in phase A/B
    const int lq = l & 3, lx = l >> 2;     // (Z-quad, XY-sub) role in phase C

    if (tid < 128) fo0L[tid] = fo0[tid];
    const float alpha = alphap[0];

    float fo1f[2][8];                      // fo1[(ly + 8h)*8 + y]
    #pragma unroll
    for (int h = 0; h < 2; ++h) {
        f32x4 a = *(const f32x4*)&fo1[(h * 8 + ly) * 8];
        f32x4 b = *(const f32x4*)&fo1[(h * 8 + ly) * 8 + 4];
        #pragma unroll
        for (int j = 0; j < 4; ++j) { fo1f[h][j] = a[j]; fo1f[h][4 + j] = b[j]; }
    }
    float fo2s[4][8];                      // fo2[(lq*4+j)*8 + z] slice
    #pragma unroll
    for (int j = 0; j < 4; ++j) {
        f32x4 a = *(const f32x4*)&fo2[(lq * 4 + j) * 8];
        f32x4 b = *(const f32x4*)&fo2[(lq * 4 + j) * 8 + 4];
        #pragma unroll
        for (int zz = 0; zz < 4; ++zz) { fo2s[j][zz] = a[zz]; fo2s[j][4 + zz] = b[zz]; }
    }

    // HOISTED phase-C constants: row-invariant, 16 chunks x f32x4 each
    f32x4 pqr[16], bqr[16];
    #pragma unroll
    for (int c2 = 0; c2 < 16; ++c2) {
        f32x4 p = *(const f32x4*)&pds[c2 * 256 + l * 4];
        pqr[c2][0] = p[0] * alpha; pqr[c2][1] = p[1] * alpha;
        pqr[c2][2] = p[2] * alpha; pqr[c2][3] = p[3] * alpha;
        bqr[c2] = *(const f32x4*)&bias[c2 * 256 + l * 4];
    }

    auto stage = [&](int b, int n) {
        const unsigned short* src = t4 + (size_t)n * 512 + l * 8;
        __builtin_amdgcn_global_load_lds(
            (const __attribute__((address_space(1))) void*)src,
            (__attribute__((address_space(3))) void*)(&t4L[w][b][l * 8]),
            16, 0, 0);
    };

    stage(0, n0);
    asm volatile("s_waitcnt vmcnt(0) lgkmcnt(0)" ::: "memory");
    __syncthreads();                       // fo0L + first t4 row visible

    #pragma unroll 1
    for (int r = 0; r < 8; ++r) {
        const int b = r & 1;
        if (r) asm volatile("s_waitcnt vmcnt(16)" ::: "memory");  // stage(r) done
                                                                  // (16 newer stores)

        // ---- phase A: rv[x] = t4[x*64+l]; t5[X][lz][ly] ----
        float rv[8];
        #pragma unroll
        for (int xx = 0; xx < 8; ++xx)
            rv[xx] = (float)t4L[w][b][xx * 64 + l];
        if (r + 1 < 8) stage(b ^ 1, n0 + r + 1);   // prefetch next row
        #pragma unroll
        for (int X = 0; X < 16; ++X) {
            f32x4 f0 = *(const f32x4*)&fo0L[X * 8];
            f32x4 f1 = *(const f32x4*)&fo0L[X * 8 + 4];
            float s = rv[0] * f0[0] + rv[1] * f0[1] + rv[2] * f0[2] + rv[3] * f0[3]
                    + rv[4] * f1[0] + rv[5] * f1[1] + rv[6] * f1[2] + rv[7] * f1[3];
            t5L[w][X * 64 + lz * 8 + ly] = s;
        }
        asm volatile("s_waitcnt lgkmcnt(0)" ::: "memory");

        // ---- phase B: lane (Y2=ly, z=lz); t6[X][Y][lz] for Y=ly, ly+8 ----
        #pragma unroll
        for (int X = 0; X < 16; ++X) {
            f32x4 u0 = *(const f32x4*)&t5L[w][X * 64 + lz * 8];
            f32x4 u1 = *(const f32x4*)&t5L[w][X * 64 + lz * 8 + 4];
            float a0 = u0[0] * fo1f[0][0] + u0[1] * fo1f[0][1] + u0[2] * fo1f[0][2] + u0[3] * fo1f[0][3]
                     + u1[0] * fo1f[0][4] + u1[1] * fo1f[0][5] + u1[2] * fo1f[0][6] + u1[3] * fo1f[0][7];
            float a1 = u0[0] * fo1f[1][0] + u0[1] * fo1f[1][1] + u0[2] * fo1f[1][2] + u0[3] * fo1f[1][3]
                     + u1[0] * fo1f[1][4] + u1[1] * fo1f[1][5] + u1[2] * fo1f[1][6] + u1[3] * fo1f[1][7];
            t6L[w][(X * 16 + ly) * 9 + lz]     = a0;
            t6L[w][(X * 16 + ly + 8) * 9 + lz] = a1;
        }
        asm volatile("s_waitcnt lgkmcnt(0)" ::: "memory");

        // ---- phase C: register constants, lane-contiguous stores ----
        float* orow = out + (size_t)(n0 + r) * 4096;
        #pragma unroll
        for (int c2 = 0; c2 < 16; ++c2) {
            const int XY = c2 * 16 + lx;
            float tv[8];
            #pragma unroll
            for (int zz = 0; zz < 8; ++zz) tv[zz] = t6L[w][XY * 9 + zz];
            f32x4 o4;
            #pragma unroll
            for (int j = 0; j < 4; ++j) {
                float t7 = tv[0] * fo2s[j][0] + tv[1] * fo2s[j][1]
                         + tv[2] * fo2s[j][2] + tv[3] * fo2s[j][3]
                         + tv[4] * fo2s[j][4] + tv[5] * fo2s[j][5]
                         + tv[6] * fo2s[j][6] + tv[7] * fo2s[j][7];
                o4[j] = t7 * pqr[c2][j] + bqr[c2][j];
            }
            *(f32x4*)&orow[c2 * 256 + l * 4] = o4;
        }
    }
}

extern "C" void kernel_launch(void* const* d_in, const int* in_sizes, int n_in,
                              void* d_out, int out_size, void* d_ws, size_t ws_size,
                              hipStream_t stream) {
    const float* x     = (const float*)d_in[0];
    const float* core  = (const float*)d_in[1];
    const float* fi0   = (const float*)d_in[2];
    const float* fi1   = (const float*)d_in[3];
    const float* fi2   = (const float*)d_in[4];
    const float* fo0   = (const float*)d_in[5];
    const float* fo1   = (const float*)d_in[6];
    const float* fo2   = (const float*)d_in[7];
    const float* pds   = (const float*)d_in[8];
    const float* alpha = (const float*)d_in[9];
    const float* bias  = (const float*)d_in[10];
    const int*   perm  = (const int*)d_in[11];
    float* outp = (float*)d_out;

    char* ws = (char*)d_ws;
    unsigned int*   cb   = (unsigned int*)(ws);                   // 512 KB
    unsigned int*   t3ws = (unsigned int*)(ws + 1048576);         // 16 MB
    unsigned short* t4   = (unsigned short*)(ws + 17825792);      // 16.75 MB

    k_corebf<<<512, 256, 0, stream>>>(core, cb);
    k_t3<<<NROWS, 256, 0, stream>>>(x, fi0, fi1, fi2, perm, t3ws);
    k_core<<<512, 256, 0, stream>>>((const __bf16*)t3ws, (const __bf16*)cb, t4);
    k_expand<<<512, 256, 0, stream>>>(t4, fo0, fo1, fo2, pds, alpha, bias, outp);
}